// Round 1
// baseline (234.384 us; speedup 1.0000x reference)
//
#include <hip/hip_runtime.h>

using half8   = __attribute__((ext_vector_type(8))) _Float16;
using f32x4   = __attribute__((ext_vector_type(4))) float;
using ushort8 = __attribute__((ext_vector_type(8))) unsigned short;

// async global->LDS, 16B per lane. LDS dest must be wave-uniform base (+lane*16 by HW).
__device__ __forceinline__ void gload16(const void* g, void* l) {
  __builtin_amdgcn_global_load_lds(
      (const __attribute__((address_space(1))) void*)g,
      (__attribute__((address_space(3))) void*)l, 16, 0, 0);
}

// ---------------- cast fp32 -> fp16 ----------------
__global__ __launch_bounds__(256) void cast_f32_f16(
    const float* __restrict__ in, unsigned short* __restrict__ out, long n) {
  long i = ((long)blockIdx.x * 256 + threadIdx.x) * 8;
  if (i >= n) return;
  float4 a = *(const float4*)(in + i);
  float4 b = *(const float4*)(in + i + 4);
  union { _Float16 h[8]; ushort8 u; } r;
  r.h[0] = (_Float16)a.x; r.h[1] = (_Float16)a.y;
  r.h[2] = (_Float16)a.z; r.h[3] = (_Float16)a.w;
  r.h[4] = (_Float16)b.x; r.h[5] = (_Float16)b.y;
  r.h[6] = (_Float16)b.z; r.h[7] = (_Float16)b.w;
  *(ushort8*)(out + i) = r.u;
}

// ---------------- NT GEMM: C[M,N] = A[M,K] * B[N,K]^T, fp16 in, fp32 acc ---------
// 128x128 tile, BK=32, 256 threads (4 waves 2x2, each 64x64 = 4x4 mfma 16x16x32).
// LDS tiles [128 rows][32 k] fp16 with 16B-granule XOR swizzle g^=((row>>1)&3),
// applied on the *global source* at staging (global_load_lds writes linearly)
// and on the ds_read address (both-sides rule).
// MODE 0: epilogue splits cols into q (scaled by 1/32), k, v fp16 [8192,1024] each.
// MODE 1: plain fp32 C (ldc=2048), batched by blockIdx.z.
// MODE 2: plain fp32 C (ldc=1024), batched by blockIdx.z.
template <int MODE>
__global__ __launch_bounds__(256) void gemm_nt(
    const unsigned short* __restrict__ Ab, const unsigned short* __restrict__ Bb,
    int K, int lda, int ldb, long sA, long sB,
    void* __restrict__ o0, void* __restrict__ o1, void* __restrict__ o2) {
  __shared__ unsigned short lsA[128 * 32];
  __shared__ unsigned short lsB[128 * 32];
  const int tid  = threadIdx.x;
  const int lane = tid & 63;
  const int wv   = tid >> 6;
  const int wr   = wv >> 1, wc = wv & 1;
  const int bm   = blockIdx.y * 128;
  const int bn   = blockIdx.x * 128;
  const int bz   = blockIdx.z;

  const unsigned short* A = Ab + (long)bz * sA;
  const unsigned short* B = Bb + (long)bz * sB;

  // staging: thread t covers LDS row srow (+64 for 2nd issue), 16B granule (t&3)
  const int srow = tid >> 2;
  const int gk   = ((tid & 3) ^ ((srow >> 1) & 3)) * 8;  // pre-swizzled source k-granule
  const unsigned short* aS0 = A + (long)(bm + srow) * lda + gk;
  const unsigned short* aS1 = A + (long)(bm + 64 + srow) * lda + gk;
  const unsigned short* bS0 = B + (long)(bn + srow) * ldb + gk;
  const unsigned short* bS1 = B + (long)(bn + 64 + srow) * ldb + gk;
  unsigned short* dA0 = lsA + wv * 512;           // wave-uniform LDS dests
  unsigned short* dA1 = lsA + 2048 + wv * 512;
  unsigned short* dB0 = lsB + wv * 512;
  unsigned short* dB1 = lsB + 2048 + wv * 512;

  // fragment read offsets (swizzled)
  const int fr   = lane & 15;
  const int fq   = lane >> 4;
  const int swzk = (fq ^ ((fr >> 1) & 3)) * 8;
  const int rbA  = (wr * 64 + fr) * 32 + swzk;    // +mi*512
  const int rbB  = (wc * 64 + fr) * 32 + swzk;    // +ni*512

  f32x4 acc[4][4] = {};

  for (int kt = 0; kt < K; kt += 32) {
    gload16(aS0 + kt, dA0);
    gload16(aS1 + kt, dA1);
    gload16(bS0 + kt, dB0);
    gload16(bS1 + kt, dB1);
    __syncthreads();  // drains vmcnt -> tiles ready
    half8 a[4], b[4];
    a[0] = *(const half8*)(lsA + rbA);
    a[1] = *(const half8*)(lsA + rbA + 512);
    a[2] = *(const half8*)(lsA + rbA + 1024);
    a[3] = *(const half8*)(lsA + rbA + 1536);
    b[0] = *(const half8*)(lsB + rbB);
    b[1] = *(const half8*)(lsB + rbB + 512);
    b[2] = *(const half8*)(lsB + rbB + 1024);
    b[3] = *(const half8*)(lsB + rbB + 1536);
#pragma unroll
    for (int mi = 0; mi < 4; ++mi)
#pragma unroll
      for (int ni = 0; ni < 4; ++ni)
        acc[mi][ni] = __builtin_amdgcn_mfma_f32_16x16x32_f16(a[mi], b[ni], acc[mi][ni], 0, 0, 0);
    __syncthreads();  // reads done before next stage overwrites
  }

  // epilogue: C/D layout col=lane&15, row=(lane>>4)*4+reg
  const int row0 = bm + wr * 64 + fq * 4;
  const int col0 = bn + wc * 64 + fr;
#pragma unroll
  for (int mi = 0; mi < 4; ++mi) {
#pragma unroll
    for (int ni = 0; ni < 4; ++ni) {
      f32x4 c = acc[mi][ni];
      const long r0 = row0 + mi * 16;
      const long e  = col0 + ni * 16;
      if constexpr (MODE == 0) {
        _Float16* q  = (_Float16*)o0;
        _Float16* kk = (_Float16*)o1;
        _Float16* vv = (_Float16*)o2;
#pragma unroll
        for (int j = 0; j < 4; ++j) {
          const long i = r0 + j;
          const float val = c[j];
          if (e < 1024)      q [i * 1024 + e]          = (_Float16)(val * 0.03125f);
          else if (e < 2048) kk[i * 1024 + (e - 1024)] = (_Float16)val;
          else               vv[i * 1024 + (e - 2048)] = (_Float16)val;
        }
      } else if constexpr (MODE == 1) {
        float* C = (float*)o0 + (long)bz * 2048 * 2048;
#pragma unroll
        for (int j = 0; j < 4; ++j) C[(r0 + j) * 2048 + e] = c[j];
      } else {
        float* C = (float*)o0 + (long)bz * 2048 * 1024;
#pragma unroll
        for (int j = 0; j < 4; ++j) C[(r0 + j) * 1024 + e] = c[j];
      }
    }
  }
}

// ---------------- transpose v [b][n][d] -> vT [b][d][n] (fp16) ----------------
__global__ __launch_bounds__(256) void transpose_v(
    const unsigned short* __restrict__ v, unsigned short* __restrict__ vT) {
  __shared__ unsigned short t[64][72];  // +8 pad
  const long b = blockIdx.z;
  const unsigned short* vb = v + b * (2048L * 1024);
  unsigned short* ob = vT + b * (1024L * 2048);
  const int n0 = blockIdx.y * 64;
  const int d0 = blockIdx.x * 64;
  const int tid = threadIdx.x;
  const int r  = tid >> 2;
  const int c0 = (tid & 3) * 16;
  const unsigned short* src = vb + (long)(n0 + r) * 1024 + d0 + c0;
  *(ushort4*)&t[r][c0]      = *(const ushort4*)(src);
  *(ushort4*)&t[r][c0 + 4]  = *(const ushort4*)(src + 4);
  *(ushort4*)&t[r][c0 + 8]  = *(const ushort4*)(src + 8);
  *(ushort4*)&t[r][c0 + 12] = *(const ushort4*)(src + 12);
  __syncthreads();
  union { unsigned short h[8]; ushort8 u; } w0, w1;
#pragma unroll
  for (int j = 0; j < 8; ++j) w0.h[j] = t[c0 + j][r];
#pragma unroll
  for (int j = 0; j < 8; ++j) w1.h[j] = t[c0 + 8 + j][r];
  unsigned short* dst = ob + (long)(d0 + r) * 2048 + n0 + c0;
  *(ushort8*)dst       = w0.u;
  *(ushort8*)(dst + 8) = w1.u;
}

// ---------------- row softmax fp32[2048] -> fp16 in-place ----------------
__global__ __launch_bounds__(256) void softmax_rows(float* __restrict__ S) {
  const long row = blockIdx.x;
  float* p = S + row * 2048;
  const int t = threadIdx.x;
  float4 v0 = *(const float4*)(p + t * 8);
  float4 v1 = *(const float4*)(p + t * 8 + 4);
  float f[8] = {v0.x, v0.y, v0.z, v0.w, v1.x, v1.y, v1.z, v1.w};
  float m = f[0];
#pragma unroll
  for (int j = 1; j < 8; ++j) m = fmaxf(m, f[j]);
  for (int o = 32; o; o >>= 1) m = fmaxf(m, __shfl_xor(m, o));
  __shared__ float redm[4];
  if (!(t & 63)) redm[t >> 6] = m;
  __syncthreads();  // also guarantees all loads complete before in-place store
  m = fmaxf(fmaxf(redm[0], redm[1]), fmaxf(redm[2], redm[3]));
  float e[8], s = 0.f;
#pragma unroll
  for (int j = 0; j < 8; ++j) { e[j] = __expf(f[j] - m); s += e[j]; }
  for (int o = 32; o; o >>= 1) s += __shfl_xor(s, o);
  __shared__ float reds[4];
  if (!(t & 63)) reds[t >> 6] = s;
  __syncthreads();
  s = reds[0] + reds[1] + reds[2] + reds[3];
  const float inv = 1.0f / s;
  union { _Float16 h[8]; ushort8 u; } r;
#pragma unroll
  for (int j = 0; j < 8; ++j) r.h[j] = (_Float16)(e[j] * inv);
  *(ushort8*)((unsigned short*)p + t * 8) = r.u;  // P fp16, lda=4096 halves
}

extern "C" void kernel_launch(void* const* d_in, const int* in_sizes, int n_in,
                              void* d_out, int out_size, void* d_ws, size_t ws_size,
                              hipStream_t stream) {
  const float* x = (const float*)d_in[0];   // [4,2048,1024]
  const float* W = (const float*)d_in[1];   // [3072,1024]
  float* out = (float*)d_out;               // [4,2048,1024] fp32
  char* ws = (char*)d_ws;

  const long MB16 = 16777216;  // 8192*1024*2 bytes
  unsigned short* q  = (unsigned short*)(ws);
  unsigned short* k  = (unsigned short*)(ws + MB16);
  unsigned short* vT = (unsigned short*)(ws + 2 * MB16);
  float*          S  = (float*)(ws + 3 * MB16);              // 67,108,864 B
  // aliased into S region (dead before S is written):
  unsigned short* xb = (unsigned short*)(ws + 3 * MB16);
  unsigned short* wb = (unsigned short*)(ws + 4 * MB16);
  unsigned short* v  = (unsigned short*)(ws + 4 * MB16 + 6291456);
  // peak ws usage: 117,440,512 B

  // 1. casts
  cast_f32_f16<<<4096, 256, 0, stream>>>(x, xb, 8388608L);
  cast_f32_f16<<<1536, 256, 0, stream>>>(W, wb, 3145728L);
  // 2. qkv = x @ W^T  (M=8192, N=3072, K=1024); q scaled by 1/32
  gemm_nt<0><<<dim3(24, 64, 1), 256, 0, stream>>>(xb, wb, 1024, 1024, 1024, 0L, 0L, q, k, v);
  // 3. v -> vT per batch
  transpose_v<<<dim3(16, 32, 4), 256, 0, stream>>>(v, vT);
  // 4. S = (q*scale) @ k^T per batch (M=N=2048, K=1024), fp32
  gemm_nt<1><<<dim3(16, 16, 4), 256, 0, stream>>>(q, k, 1024, 1024, 1024,
                                                  2048L * 1024, 2048L * 1024, S, nullptr, nullptr);
  // 5. row softmax, P fp16 in place (row pitch 4096 halves)
  softmax_rows<<<8192, 256, 0, stream>>>(S);
  // 6. out = P @ vT^T per batch (M=2048, N=1024, K=2048), fp32
  gemm_nt<2><<<dim3(8, 16, 4), 256, 0, stream>>>((unsigned short*)S, vT, 2048, 4096, 2048,
                                                 2048L * 4096, 1024L * 2048, out, nullptr, nullptr);
}

// Round 2
// 193.006 us; speedup vs baseline: 1.2144x; 1.2144x over previous
//
#include <hip/hip_runtime.h>

using half8   = __attribute__((ext_vector_type(8))) _Float16;
using f32x4   = __attribute__((ext_vector_type(4))) float;
using ushort8 = __attribute__((ext_vector_type(8))) unsigned short;

__device__ __forceinline__ void gload16(const void* g, void* l) {
  __builtin_amdgcn_global_load_lds(
      (const __attribute__((address_space(1))) void*)g,
      (__attribute__((address_space(3))) void*)l, 16, 0, 0);
}

// ---------------- cast fp32 -> fp16 ----------------
__global__ __launch_bounds__(256) void cast_f32_f16(
    const float* __restrict__ in, unsigned short* __restrict__ out, long n) {
  long i = ((long)blockIdx.x * 256 + threadIdx.x) * 8;
  if (i >= n) return;
  float4 a = *(const float4*)(in + i);
  float4 b = *(const float4*)(in + i + 4);
  union { _Float16 h[8]; ushort8 u; } r;
  r.h[0] = (_Float16)a.x; r.h[1] = (_Float16)a.y;
  r.h[2] = (_Float16)a.z; r.h[3] = (_Float16)a.w;
  r.h[4] = (_Float16)b.x; r.h[5] = (_Float16)b.y;
  r.h[6] = (_Float16)b.z; r.h[7] = (_Float16)b.w;
  *(ushort8*)(out + i) = r.u;
}

// ============ 8-wave phase-interleaved NT GEMM: C[M,N] = A[M,K]*B[N,K]^T ============
// 512 threads = 8 waves (2 M x 4 N). BK=64. Per-wave tile: (M_REP*16) x (N_REP*16).
// BM = 32*M_REP, BN = 64*N_REP. LDS: double-buffered A,B K-tiles, XOR-swizzled
// 16B granules (g ^= row&7), written via pre-swizzled global source (gload_lds
// writes linearly) and read with the same XOR. NPH = M_REP/2 phases per K-tile,
// 16 MFMA each (2 m-tiles x N_REP x 2 ksteps); B-frags for the whole K-tile are
// read in phase 0 and held in registers. Next K-tile staging is issued entirely
// in phase 0; a single counted drain (vmcnt(0)) happens at the last phase's
// barrier, >= 2 phases after issue. Raw s_barrier everywhere (no __syncthreads
// -> no forced vmcnt(0) per barrier).
template <int MODE, int M_REP, int N_REP>
__global__ __launch_bounds__(512, 2) void gemm8p(
    const unsigned short* __restrict__ Ab, const unsigned short* __restrict__ Bb,
    int K, int lda, int ldb, long sA, long sB,
    void* __restrict__ o0, void* __restrict__ o1, void* __restrict__ o2) {
  static_assert(M_REP % 2 == 0, "");
  constexpr int BM  = 32 * M_REP;
  constexpr int BN  = 64 * N_REP;
  constexpr int ASZ = BM * 64;          // elems per A buffer
  constexpr int BSZ = BN * 64;          // elems per B buffer
  constexpr int AI  = BM / 64;          // staging issues for A
  constexpr int BI  = BN / 64;
  constexpr int NPH = M_REP / 2;
  __shared__ unsigned short lds[2 * ASZ + 2 * BSZ];

  const int tid  = threadIdx.x;
  const int lane = tid & 63;
  const int wv   = tid >> 6;
  const int wr   = wv >> 2, wc = wv & 3;
  const int fr   = lane & 15, fq = lane >> 4;
  const int bm   = blockIdx.y * BM;
  const int bn   = blockIdx.x * BN;
  const int bz   = blockIdx.z;

  const unsigned short* A = Ab + (long)bz * sA;
  const unsigned short* B = Bb + (long)bz * sB;

  // staging map: thread t -> row t>>3 (of 64-row issue block), 16B granule t&7,
  // source pre-swizzled: granule (t&7) ^ (row&7)
  const int row_s = tid >> 3;
  const int col_s = ((tid & 7) ^ (row_s & 7)) * 8;
  const unsigned short* aS = A + (long)(bm + row_s) * lda + col_s;
  const unsigned short* bS = B + (long)(bn + row_s) * ldb + col_s;

  // fragment read offsets (bytes), swizzle XOR value = fr&7 (rows are base+fr, base%16==0)
  const int kg0 = ((0 * 4 + fq) ^ (fr & 7)) * 16;
  const int kg1 = ((1 * 4 + fq) ^ (fr & 7)) * 16;
  const char* ldsb = (const char*)lds;
  const int aRd = (wr * (BM / 2) + fr) * 128;      // + mi*2048 + kg
  const int bRd = (wc * (16 * N_REP) + fr) * 128;  // + ni*2048 + kg

  f32x4 acc[M_REP][N_REP] = {};
  half8 b_frag[N_REP][2];

  const int nt = K / 64;

  // prologue: stage tile 0 into buffer 0
  {
    unsigned short* dA = lds + wv * 512;
    unsigned short* dB = lds + 2 * ASZ + wv * 512;
#pragma unroll
    for (int j = 0; j < AI; ++j) gload16(aS + (long)j * 64 * lda, dA + j * 4096);
#pragma unroll
    for (int j = 0; j < BI; ++j) gload16(bS + (long)j * 64 * ldb, dB + j * 4096);
  }
  asm volatile("s_waitcnt vmcnt(0)" ::: "memory");
  __builtin_amdgcn_s_barrier();

  for (int t = 0; t < nt; ++t) {
    const int  cur = t & 1;
    const bool pf  = (t + 1 < nt);
    const char* lA = ldsb + (size_t)(cur * ASZ) * 2;
    const char* lB = ldsb + (size_t)(2 * ASZ + cur * BSZ) * 2;
#pragma unroll
    for (int p = 0; p < NPH; ++p) {
      half8 a_frag[2][2];
      if (p == 0) {
#pragma unroll
        for (int ni = 0; ni < N_REP; ++ni) {
          b_frag[ni][0] = *(const half8*)(lB + bRd + ni * 2048 + kg0);
          b_frag[ni][1] = *(const half8*)(lB + bRd + ni * 2048 + kg1);
        }
      }
#pragma unroll
      for (int i = 0; i < 2; ++i) {
        a_frag[i][0] = *(const half8*)(lA + aRd + (2 * p + i) * 2048 + kg0);
        a_frag[i][1] = *(const half8*)(lA + aRd + (2 * p + i) * 2048 + kg1);
      }
      if (p == 0 && pf) {  // stage next K-tile, all issues up front
        const long kt = (long)(t + 1) * 64;
        unsigned short* dA = lds + (cur ^ 1) * ASZ + wv * 512;
        unsigned short* dB = lds + 2 * ASZ + (cur ^ 1) * BSZ + wv * 512;
#pragma unroll
        for (int j = 0; j < AI; ++j) gload16(aS + (long)j * 64 * lda + kt, dA + j * 4096);
#pragma unroll
        for (int j = 0; j < BI; ++j) gload16(bS + (long)j * 64 * ldb + kt, dB + j * 4096);
      }
      __builtin_amdgcn_sched_barrier(0);
      __builtin_amdgcn_s_barrier();                       // phase barrier 1
      asm volatile("s_waitcnt lgkmcnt(0)" ::: "memory");  // own ds_reads done
      __builtin_amdgcn_sched_barrier(0);                  // rule #18 fence
      __builtin_amdgcn_s_setprio(1);
#pragma unroll
      for (int ks = 0; ks < 2; ++ks)
#pragma unroll
        for (int i = 0; i < 2; ++i)
#pragma unroll
          for (int ni = 0; ni < N_REP; ++ni)
            acc[2 * p + i][ni] = __builtin_amdgcn_mfma_f32_16x16x32_f16(
                a_frag[i][ks], b_frag[ni][ks], acc[2 * p + i][ni], 0, 0, 0);
      __builtin_amdgcn_s_setprio(0);
      __builtin_amdgcn_sched_barrier(0);
      if (p == NPH - 1 && pf)  // once per K-tile: next tile fully landed
        asm volatile("s_waitcnt vmcnt(0)" ::: "memory");
      __builtin_amdgcn_s_barrier();                       // phase barrier 2
    }
  }

  // epilogue: C/D layout col=lane&15, row=fq*4+reg
  const int row0 = bm + wr * (BM / 2) + fq * 4;
  const int col0 = bn + wc * (16 * N_REP) + fr;
#pragma unroll
  for (int mi = 0; mi < M_REP; ++mi) {
#pragma unroll
    for (int ni = 0; ni < N_REP; ++ni) {
      f32x4 c = acc[mi][ni];
      const long r0 = row0 + mi * 16;
      const long e  = col0 + ni * 16;
      if constexpr (MODE == 0) {
        _Float16* q  = (_Float16*)o0;
        _Float16* kk = (_Float16*)o1;
        _Float16* vv = (_Float16*)o2;
#pragma unroll
        for (int j = 0; j < 4; ++j) {
          const long i = r0 + j;
          const float val = c[j];
          if (e < 1024)      q [i * 1024 + e]          = (_Float16)(val * 0.03125f);
          else if (e < 2048) kk[i * 1024 + (e - 1024)] = (_Float16)val;
          else               vv[i * 1024 + (e - 2048)] = (_Float16)val;
        }
      } else if constexpr (MODE == 1) {
        float* C = (float*)o0 + (long)bz * 2048 * 2048;
#pragma unroll
        for (int j = 0; j < 4; ++j) C[(r0 + j) * 2048 + e] = c[j];
      } else {
        float* C = (float*)o0 + (long)bz * 2048 * 1024;
#pragma unroll
        for (int j = 0; j < 4; ++j) C[(r0 + j) * 1024 + e] = c[j];
      }
    }
  }
}

// ---------------- transpose v [b][n][d] -> vT [b][d][n] (fp16) ----------------
__global__ __launch_bounds__(256) void transpose_v(
    const unsigned short* __restrict__ v, unsigned short* __restrict__ vT) {
  __shared__ unsigned short t[64][72];  // +8 pad
  const long b = blockIdx.z;
  const unsigned short* vb = v + b * (2048L * 1024);
  unsigned short* ob = vT + b * (1024L * 2048);
  const int n0 = blockIdx.y * 64;
  const int d0 = blockIdx.x * 64;
  const int tid = threadIdx.x;
  const int r  = tid >> 2;
  const int c0 = (tid & 3) * 16;
  const unsigned short* src = vb + (long)(n0 + r) * 1024 + d0 + c0;
  *(ushort4*)&t[r][c0]      = *(const ushort4*)(src);
  *(ushort4*)&t[r][c0 + 4]  = *(const ushort4*)(src + 4);
  *(ushort4*)&t[r][c0 + 8]  = *(const ushort4*)(src + 8);
  *(ushort4*)&t[r][c0 + 12] = *(const ushort4*)(src + 12);
  __syncthreads();
  union { unsigned short h[8]; ushort8 u; } w0, w1;
#pragma unroll
  for (int j = 0; j < 8; ++j) w0.h[j] = t[c0 + j][r];
#pragma unroll
  for (int j = 0; j < 8; ++j) w1.h[j] = t[c0 + 8 + j][r];
  unsigned short* dst = ob + (long)(d0 + r) * 2048 + n0 + c0;
  *(ushort8*)dst       = w0.u;
  *(ushort8*)(dst + 8) = w1.u;
}

// ---------------- row softmax fp32[2048] -> fp16 in-place ----------------
__global__ __launch_bounds__(256) void softmax_rows(float* __restrict__ S) {
  const long row = blockIdx.x;
  float* p = S + row * 2048;
  const int t = threadIdx.x;
  float4 v0 = *(const float4*)(p + t * 8);
  float4 v1 = *(const float4*)(p + t * 8 + 4);
  float f[8] = {v0.x, v0.y, v0.z, v0.w, v1.x, v1.y, v1.z, v1.w};
  float m = f[0];
#pragma unroll
  for (int j = 1; j < 8; ++j) m = fmaxf(m, f[j]);
  for (int o = 32; o; o >>= 1) m = fmaxf(m, __shfl_xor(m, o));
  __shared__ float redm[4];
  if (!(t & 63)) redm[t >> 6] = m;
  __syncthreads();
  m = fmaxf(fmaxf(redm[0], redm[1]), fmaxf(redm[2], redm[3]));
  float e[8], s = 0.f;
#pragma unroll
  for (int j = 0; j < 8; ++j) { e[j] = __expf(f[j] - m); s += e[j]; }
  for (int o = 32; o; o >>= 1) s += __shfl_xor(s, o);
  __shared__ float reds[4];
  if (!(t & 63)) reds[t >> 6] = s;
  __syncthreads();
  s = reds[0] + reds[1] + reds[2] + reds[3];
  const float inv = 1.0f / s;
  union { _Float16 h[8]; ushort8 u; } r;
#pragma unroll
  for (int j = 0; j < 8; ++j) r.h[j] = (_Float16)(e[j] * inv);
  *(ushort8*)((unsigned short*)p + t * 8) = r.u;  // P fp16, row pitch 4096 halves
}

extern "C" void kernel_launch(void* const* d_in, const int* in_sizes, int n_in,
                              void* d_out, int out_size, void* d_ws, size_t ws_size,
                              hipStream_t stream) {
  const float* x = (const float*)d_in[0];   // [4,2048,1024]
  const float* W = (const float*)d_in[1];   // [3072,1024]
  float* out = (float*)d_out;               // [4,2048,1024] fp32
  char* ws = (char*)d_ws;

  const long MB16 = 16777216;  // 8192*1024*2 bytes
  unsigned short* q  = (unsigned short*)(ws);
  unsigned short* k  = (unsigned short*)(ws + MB16);
  unsigned short* vT = (unsigned short*)(ws + 2 * MB16);
  float*          S  = (float*)(ws + 3 * MB16);              // 64 MiB
  // aliased into S region (dead before S is written):
  unsigned short* xb = (unsigned short*)(ws + 3 * MB16);
  unsigned short* wb = (unsigned short*)(ws + 4 * MB16);
  unsigned short* v  = (unsigned short*)(ws + 4 * MB16 + 6291456);

  // 1. casts
  cast_f32_f16<<<4096, 256, 0, stream>>>(x, xb, 8388608L);
  cast_f32_f16<<<1536, 256, 0, stream>>>(W, wb, 3145728L);
  // 2. qkv = x @ W^T  (M=8192, N=3072, K=1024), BM=128 BN=256 -> 768 blocks
  gemm8p<0, 4, 4><<<dim3(12, 64, 1), 512, 0, stream>>>(
      xb, wb, 1024, 1024, 1024, 0L, 0L, q, k, v);
  // 3. v -> vT per batch
  transpose_v<<<dim3(16, 32, 4), 256, 0, stream>>>(v, vT);
  // 4. S = (q*scale) @ k^T per batch (M=N=2048, K=1024), BM=BN=256 -> 256 blocks
  gemm8p<1, 8, 4><<<dim3(8, 8, 4), 512, 0, stream>>>(
      q, k, 1024, 1024, 1024, 2048L * 1024, 2048L * 1024, S, nullptr, nullptr);
  // 5. row softmax, P fp16 in place (row pitch 4096 halves)
  softmax_rows<<<8192, 256, 0, stream>>>(S);
  // 6. out = P @ vT^T per batch (M=2048, N=1024, K=2048), BM=256 BN=128 -> 256 blocks
  gemm8p<2, 8, 2><<<dim3(8, 8, 4), 512, 0, stream>>>(
      (unsigned short*)S, vT, 2048, 4096, 2048, 2048L * 4096, 1024L * 2048,
      out, nullptr, nullptr);
}

// Round 3
// 186.709 us; speedup vs baseline: 1.2553x; 1.0337x over previous
//
#include <hip/hip_runtime.h>

using half8   = __attribute__((ext_vector_type(8))) _Float16;
using f32x4   = __attribute__((ext_vector_type(4))) float;
using ushort8 = __attribute__((ext_vector_type(8))) unsigned short;

__device__ __forceinline__ void gload16(const void* g, void* l) {
  __builtin_amdgcn_global_load_lds(
      (const __attribute__((address_space(1))) void*)g,
      (__attribute__((address_space(3))) void*)l, 16, 0, 0);
}

// ---------------- cast fp32 -> fp16 ----------------
__global__ __launch_bounds__(256) void cast_f32_f16(
    const float* __restrict__ in, unsigned short* __restrict__ out, long n) {
  long i = ((long)blockIdx.x * 256 + threadIdx.x) * 8;
  if (i >= n) return;
  float4 a = *(const float4*)(in + i);
  float4 b = *(const float4*)(in + i + 4);
  union { _Float16 h[8]; ushort8 u; } r;
  r.h[0] = (_Float16)a.x; r.h[1] = (_Float16)a.y;
  r.h[2] = (_Float16)a.z; r.h[3] = (_Float16)a.w;
  r.h[4] = (_Float16)b.x; r.h[5] = (_Float16)b.y;
  r.h[6] = (_Float16)b.z; r.h[7] = (_Float16)b.w;
  *(ushort8*)(out + i) = r.u;
}

// ============ 8-wave counted-vmcnt NT GEMM: C[M,N] = A[M,K]*B[N,K]^T ============
// BM=256 fixed, BN=64*N_REP, BK=64, 512 threads (2M x 4N waves), per-wave
// 128 x 16*N_REP, NPH=4 phases/K-tile (16x16x32 f16 MFMA, M_REP=8).
// LDS: 2 A-slots (16 KiB each... 32 KiB) + 2 B-slots, XOR-swizzled 16B granules.
// Counted-vmcnt pipeline with 2-tile LDS:
//   - B-frags for the whole tile are register-held from phase 0 -> B slot is
//     DEAD after phase 0's barrier; tile t+2's B units stage into the CURRENT
//     B slot at phases 2,3 (issue at p2 is after p1's barrier => all waves
//     completed their p0 lgkmcnt(0) => no read-write race).
//   - A units of t+1 stage at phases 0,1 into A slot cur^1.
//   - Boundary wait = vmcnt(N_REP): outstanding then = [B(t+1),A(t+1),B(t+2)],
//     allowing exactly t+2's N_REP B-loads to stay in flight. Never 0 in
//     steady state (T4). Prologue: A(0),B(0),B(1) then vmcnt(N_REP).
template <int MODE, int N_REP>
__global__ __launch_bounds__(512, 2) void gemm8p(
    const unsigned short* __restrict__ Ab, const unsigned short* __restrict__ Bb,
    int K, int lda, int ldb, long sA, long sB,
    void* __restrict__ o0, void* __restrict__ o1, void* __restrict__ o2) {
  constexpr int BM  = 256;
  constexpr int BN  = 64 * N_REP;
  constexpr int ASZ = BM * 64;   // 16384 elems per A slot
  constexpr int BSZ = BN * 64;
  __shared__ unsigned short lds[2 * ASZ + 2 * BSZ];

  const int tid  = threadIdx.x;
  const int lane = tid & 63;
  const int wv   = tid >> 6;
  const int wr   = wv >> 2, wc = wv & 3;
  const int fr   = lane & 15, fq = lane >> 4;
  const int bm   = blockIdx.y * BM;
  const int bn   = blockIdx.x * BN;
  const int bz   = blockIdx.z;

  const unsigned short* A = Ab + (long)bz * sA;
  const unsigned short* B = Bb + (long)bz * sB;

  // staging map: thread t -> row tid>>3 within a 64-row issue unit, 16B granule
  // tid&7, source pre-swizzled (gload_lds writes linearly; read applies same XOR)
  const int row_s = tid >> 3;
  const int col_s = ((tid & 7) ^ (row_s & 7)) * 8;
  const unsigned short* aS = A + (long)(bm + row_s) * lda + col_s;
  const unsigned short* bS = B + (long)(bn + row_s) * ldb + col_s;
  unsigned short* ldsA = lds;
  unsigned short* ldsB = lds + 2 * ASZ;

  // fragment read offsets (bytes)
  const int kg0 = ((0 * 4 + fq) ^ (fr & 7)) * 16;
  const int kg1 = ((1 * 4 + fq) ^ (fr & 7)) * 16;
  const int aRd = (wr * 128 + fr) * 128;           // + mt*2048 + kg
  const int bRd = (wc * (16 * N_REP) + fr) * 128;  // + ni*2048 + kg

  f32x4 acc[8][N_REP] = {};
  half8 b_frag[N_REP][2];

  const int nt = K / 64;

  // ---- prologue: A(0) [4 loads], B(0) [N_REP], B(1) [N_REP] ----
#pragma unroll
  for (int i = 0; i < 4; ++i)
    gload16(aS + (long)(i * 64) * lda, ldsA + i * 4096 + wv * 512);
#pragma unroll
  for (int j = 0; j < N_REP; ++j)
    gload16(bS + (long)(j * 64) * ldb, ldsB + j * 4096 + wv * 512);
#pragma unroll
  for (int j = 0; j < N_REP; ++j)
    gload16(bS + (long)(j * 64) * ldb + 64, ldsB + BSZ + j * 4096 + wv * 512);
  if constexpr (N_REP == 2)      asm volatile("s_waitcnt vmcnt(2)" ::: "memory");
  else if constexpr (N_REP == 3) asm volatile("s_waitcnt vmcnt(3)" ::: "memory");
  else                           asm volatile("s_waitcnt vmcnt(4)" ::: "memory");
  __builtin_amdgcn_s_barrier();

  for (int t = 0; t < nt; ++t) {
    const int cur = t & 1;
    const char* lA = (const char*)(ldsA + cur * ASZ);
    const char* lB = (const char*)(ldsB + cur * BSZ);
#pragma unroll
    for (int p = 0; p < 4; ++p) {
      half8 a_frag[2][2];
      if (p == 0) {
#pragma unroll
        for (int ni = 0; ni < N_REP; ++ni) {
          b_frag[ni][0] = *(const half8*)(lB + bRd + ni * 2048 + kg0);
          b_frag[ni][1] = *(const half8*)(lB + bRd + ni * 2048 + kg1);
        }
      }
#pragma unroll
      for (int i = 0; i < 2; ++i) {
        a_frag[i][0] = *(const half8*)(lA + aRd + (2 * p + i) * 2048 + kg0);
        a_frag[i][1] = *(const half8*)(lA + aRd + (2 * p + i) * 2048 + kg1);
      }
      // staged issues (counted pipeline)
      if (p == 0 && t + 1 < nt) {        // A(t+1) rows 0..127 -> slot cur^1
        unsigned short* d = ldsA + (cur ^ 1) * ASZ + wv * 512;
        const long kt = (long)(t + 1) * 64;
        gload16(aS + kt, d);
        gload16(aS + (long)64 * lda + kt, d + 4096);
      }
      if (p == 1 && t + 1 < nt) {        // A(t+1) rows 128..255
        unsigned short* d = ldsA + (cur ^ 1) * ASZ + 8192 + wv * 512;
        const long kt = (long)(t + 1) * 64;
        gload16(aS + (long)128 * lda + kt, d);
        gload16(aS + (long)192 * lda + kt, d + 4096);
      }
      if (p == 2 && t + 2 < nt) {        // B(t+2) first units -> slot cur (dead after p0)
        const long kt = (long)(t + 2) * 64;
#pragma unroll
        for (int j = 0; j < N_REP / 2; ++j)
          gload16(bS + (long)(j * 64) * ldb + kt, ldsB + cur * BSZ + j * 4096 + wv * 512);
      }
      if (p == 3 && t + 2 < nt) {        // B(t+2) remaining units
        const long kt = (long)(t + 2) * 64;
#pragma unroll
        for (int j = N_REP / 2; j < N_REP; ++j)
          gload16(bS + (long)(j * 64) * ldb + kt, ldsB + cur * BSZ + j * 4096 + wv * 512);
      }
      __builtin_amdgcn_sched_barrier(0);
      __builtin_amdgcn_s_barrier();                       // phase barrier 1
      asm volatile("s_waitcnt lgkmcnt(0)" ::: "memory");
      __builtin_amdgcn_sched_barrier(0);                  // rule #18 fence
      __builtin_amdgcn_s_setprio(1);
#pragma unroll
      for (int ks = 0; ks < 2; ++ks)
#pragma unroll
        for (int i = 0; i < 2; ++i)
#pragma unroll
          for (int ni = 0; ni < N_REP; ++ni)
            acc[2 * p + i][ni] = __builtin_amdgcn_mfma_f32_16x16x32_f16(
                a_frag[i][ks], b_frag[ni][ks], acc[2 * p + i][ni], 0, 0, 0);
      __builtin_amdgcn_s_setprio(0);
      __builtin_amdgcn_sched_barrier(0);
      if (p == 3) {                      // counted boundary wait: t+1 landed,
        if (t + 2 < nt) {                // t+2's B (N_REP loads) may stay in flight
          if constexpr (N_REP == 2)      asm volatile("s_waitcnt vmcnt(2)" ::: "memory");
          else if constexpr (N_REP == 3) asm volatile("s_waitcnt vmcnt(3)" ::: "memory");
          else                           asm volatile("s_waitcnt vmcnt(4)" ::: "memory");
        } else {
          asm volatile("s_waitcnt vmcnt(0)" ::: "memory");
        }
      }
      __builtin_amdgcn_s_barrier();                       // phase barrier 2
    }
  }

  // epilogue: C/D layout col=lane&15, row=fq*4+reg
  const int row0 = bm + wr * 128 + fq * 4;
  const int col0 = bn + wc * (16 * N_REP) + fr;
#pragma unroll
  for (int mi = 0; mi < 8; ++mi) {
#pragma unroll
    for (int ni = 0; ni < N_REP; ++ni) {
      f32x4 c = acc[mi][ni];
      const long r0 = row0 + mi * 16;
      const long e  = col0 + ni * 16;
      if constexpr (MODE == 0) {
        _Float16* q  = (_Float16*)o0;
        _Float16* kk = (_Float16*)o1;
        _Float16* vv = (_Float16*)o2;
#pragma unroll
        for (int j = 0; j < 4; ++j) {
          const long i = r0 + j;
          const float val = c[j];
          if (e < 1024)      q [i * 1024 + e]          = (_Float16)(val * 0.03125f);
          else if (e < 2048) kk[i * 1024 + (e - 1024)] = (_Float16)val;
          else               vv[i * 1024 + (e - 2048)] = (_Float16)val;
        }
      } else if constexpr (MODE == 1) {
        float* C = (float*)o0 + (long)bz * 2048 * 2048;
#pragma unroll
        for (int j = 0; j < 4; ++j) C[(r0 + j) * 2048 + e] = c[j];
      } else {
        float* C = (float*)o0 + (long)bz * 2048 * 1024;
#pragma unroll
        for (int j = 0; j < 4; ++j) C[(r0 + j) * 1024 + e] = c[j];
      }
    }
  }
}

// ---------------- transpose v [b][n][d] -> vT [b][d][n] (fp16) ----------------
__global__ __launch_bounds__(256) void transpose_v(
    const unsigned short* __restrict__ v, unsigned short* __restrict__ vT) {
  __shared__ unsigned short t[64][72];  // +8 pad
  const long b = blockIdx.z;
  const unsigned short* vb = v + b * (2048L * 1024);
  unsigned short* ob = vT + b * (1024L * 2048);
  const int n0 = blockIdx.y * 64;
  const int d0 = blockIdx.x * 64;
  const int tid = threadIdx.x;
  const int r  = tid >> 2;
  const int c0 = (tid & 3) * 16;
  const unsigned short* src = vb + (long)(n0 + r) * 1024 + d0 + c0;
  *(ushort4*)&t[r][c0]      = *(const ushort4*)(src);
  *(ushort4*)&t[r][c0 + 4]  = *(const ushort4*)(src + 4);
  *(ushort4*)&t[r][c0 + 8]  = *(const ushort4*)(src + 8);
  *(ushort4*)&t[r][c0 + 12] = *(const ushort4*)(src + 12);
  __syncthreads();
  union { unsigned short h[8]; ushort8 u; } w0, w1;
#pragma unroll
  for (int j = 0; j < 8; ++j) w0.h[j] = t[c0 + j][r];
#pragma unroll
  for (int j = 0; j < 8; ++j) w1.h[j] = t[c0 + 8 + j][r];
  unsigned short* dst = ob + (long)(d0 + r) * 2048 + n0 + c0;
  *(ushort8*)dst       = w0.u;
  *(ushort8*)(dst + 8) = w1.u;
}

// ---------------- row softmax fp32[2048] -> fp16 in-place ----------------
__global__ __launch_bounds__(256) void softmax_rows(float* __restrict__ S) {
  const long row = blockIdx.x;
  float* p = S + row * 2048;
  const int t = threadIdx.x;
  float4 v0 = *(const float4*)(p + t * 8);
  float4 v1 = *(const float4*)(p + t * 8 + 4);
  float f[8] = {v0.x, v0.y, v0.z, v0.w, v1.x, v1.y, v1.z, v1.w};
  float m = f[0];
#pragma unroll
  for (int j = 1; j < 8; ++j) m = fmaxf(m, f[j]);
  for (int o = 32; o; o >>= 1) m = fmaxf(m, __shfl_xor(m, o));
  __shared__ float redm[4];
  if (!(t & 63)) redm[t >> 6] = m;
  __syncthreads();
  m = fmaxf(fmaxf(redm[0], redm[1]), fmaxf(redm[2], redm[3]));
  float e[8], s = 0.f;
#pragma unroll
  for (int j = 0; j < 8; ++j) { e[j] = __expf(f[j] - m); s += e[j]; }
  for (int o = 32; o; o >>= 1) s += __shfl_xor(s, o);
  __shared__ float reds[4];
  if (!(t & 63)) reds[t >> 6] = s;
  __syncthreads();
  s = reds[0] + reds[1] + reds[2] + reds[3];
  const float inv = 1.0f / s;
  union { _Float16 h[8]; ushort8 u; } r;
#pragma unroll
  for (int j = 0; j < 8; ++j) r.h[j] = (_Float16)(e[j] * inv);
  *(ushort8*)((unsigned short*)p + t * 8) = r.u;  // P fp16, row pitch 4096 halves
}

extern "C" void kernel_launch(void* const* d_in, const int* in_sizes, int n_in,
                              void* d_out, int out_size, void* d_ws, size_t ws_size,
                              hipStream_t stream) {
  const float* x = (const float*)d_in[0];   // [4,2048,1024]
  const float* W = (const float*)d_in[1];   // [3072,1024]
  float* out = (float*)d_out;               // [4,2048,1024] fp32
  char* ws = (char*)d_ws;

  const long MB16 = 16777216;  // 8192*1024*2 bytes
  unsigned short* q  = (unsigned short*)(ws);
  unsigned short* k  = (unsigned short*)(ws + MB16);
  unsigned short* vT = (unsigned short*)(ws + 2 * MB16);
  float*          S  = (float*)(ws + 3 * MB16);              // 64 MiB
  // aliased into S region (dead before S is written):
  unsigned short* xb = (unsigned short*)(ws + 3 * MB16);
  unsigned short* wb = (unsigned short*)(ws + 4 * MB16);
  unsigned short* v  = (unsigned short*)(ws + 4 * MB16 + 6291456);

  // 1. casts
  cast_f32_f16<<<4096, 256, 0, stream>>>(x, xb, 8388608L);
  cast_f32_f16<<<1536, 256, 0, stream>>>(W, wb, 3145728L);
  // 2. qkv = x @ W^T (M=8192, N=3072, K=1024), BM=256 BN=192 -> 512 blocks (2 rounds)
  gemm8p<0, 3><<<dim3(16, 32, 1), 512, 0, stream>>>(
      xb, wb, 1024, 1024, 1024, 0L, 0L, q, k, v);
  // 3. v -> vT per batch
  transpose_v<<<dim3(16, 32, 4), 256, 0, stream>>>(v, vT);
  // 4. S = (q*scale) @ k^T per batch (M=N=2048, K=1024), BM=BN=256 -> 256 blocks
  gemm8p<1, 4><<<dim3(8, 8, 4), 512, 0, stream>>>(
      q, k, 1024, 1024, 1024, 2048L * 1024, 2048L * 1024, S, nullptr, nullptr);
  // 5. row softmax, P fp16 in place (row pitch 4096 halves)
  softmax_rows<<<8192, 256, 0, stream>>>(S);
  // 6. out = P @ vT^T per batch (M=2048, N=1024, K=2048), BM=256 BN=128 -> 256 blocks
  gemm8p<2, 2><<<dim3(8, 8, 4), 512, 0, stream>>>(
      (unsigned short*)S, vT, 2048, 4096, 2048, 2048L * 4096, 1024L * 2048,
      out, nullptr, nullptr);
}